// Round 10
// baseline (32438.565 us; speedup 1.0000x reference)
//
#include <hip/hip_runtime.h>
#include <cstdint>

typedef float vf2 __attribute__((ext_vector_type(2)));

#define GB_M 128
#define GB_N 64
#define GB_K 16

// C[m,n] = act( sum_k A[row(m),k]*B[n,k] + bias[n] )
__global__ __launch_bounds__(256) void gemm_bt_f32(
    const float* __restrict__ A, const float* __restrict__ B,
    const float* __restrict__ bias, float* __restrict__ C,
    int Mc, int N, int K, int tc_shift, int Tfull, int t0, int act)
{
  __shared__ float As[GB_K][GB_M + 4];
  __shared__ float Bs[GB_K][GB_N + 4];
  const int tid = threadIdx.x;
  const int m0 = blockIdx.y * GB_M;
  const int n0 = blockIdx.x * GB_N;
  const int tx = tid & 15;
  const int ty = tid >> 4;

  const int tcmask = (1 << tc_shift) - 1;
  int arow[2];
#pragma unroll
  for (int i = 0; i < 2; i++) {
    int f = tid + i * 256;
    int row = f >> 2;
    int rc = m0 + row;
    arow[i] = (rc >> tc_shift) * Tfull + t0 + (rc & tcmask);
  }
  const int akq = tid & 3;
  const int brow = tid >> 2;
  const int bn = n0 + brow;

  vf2 acc2[4][4];
#pragma unroll
  for (int i = 0; i < 4; i++)
#pragma unroll
    for (int j = 0; j < 4; j++) acc2[i][j] = (vf2)(0.f);

  for (int k0 = 0; k0 < K; k0 += GB_K) {
#pragma unroll
    for (int i = 0; i < 2; i++) {
      int f = tid + i * 256;
      int row = f >> 2;
      float4 v = *(const float4*)(A + (size_t)arow[i] * K + k0 + akq * 4);
      As[akq * 4 + 0][row] = v.x; As[akq * 4 + 1][row] = v.y;
      As[akq * 4 + 2][row] = v.z; As[akq * 4 + 3][row] = v.w;
    }
    {
      float4 v = make_float4(0.f, 0.f, 0.f, 0.f);
      if (bn < N) v = *(const float4*)(B + (size_t)bn * K + k0 + akq * 4);
      Bs[akq * 4 + 0][brow] = v.x; Bs[akq * 4 + 1][brow] = v.y;
      Bs[akq * 4 + 2][brow] = v.z; Bs[akq * 4 + 3][brow] = v.w;
    }
    __syncthreads();
#pragma unroll
    for (int k = 0; k < GB_K; k++) {
      float4 a0 = *(const float4*)&As[k][ty * 8];
      float4 a1 = *(const float4*)&As[k][ty * 8 + 4];
      float4 b0 = *(const float4*)&Bs[k][tx * 4];
      vf2 a2[4];
      a2[0] = (vf2){a0.x, a0.y}; a2[1] = (vf2){a0.z, a0.w};
      a2[2] = (vf2){a1.x, a1.y}; a2[3] = (vf2){a1.z, a1.w};
      float bv[4] = {b0.x, b0.y, b0.z, b0.w};
#pragma unroll
      for (int j = 0; j < 4; j++) {
        vf2 bs = (vf2){bv[j], bv[j]};
#pragma unroll
        for (int ip = 0; ip < 4; ip++)
          acc2[ip][j] = __builtin_elementwise_fma(a2[ip], bs, acc2[ip][j]);
      }
    }
    __syncthreads();
  }

#pragma unroll
  for (int j = 0; j < 4; j++) {
    int n = n0 + tx * 4 + j;
    if (n >= N) continue;
    float bz = bias[n];
#pragma unroll
    for (int i = 0; i < 8; i++) {
      int m = m0 + ty * 8 + i;
      float x = ((i & 1) ? acc2[i >> 1][j].y : acc2[i >> 1][j].x) + bz;
      if (act == 1) {
        x = 1.0507009873554805f * (x > 0.f ? x : 1.6732632423543772f * (__expf(x) - 1.f));
      } else if (act == 2) {
        x = tanhf(x);
      }
      C[(size_t)m * N + n] = x;
    }
  }
}

#define RT 384
#define RNWG 256

// Round-12 (resubmit after infra failure): DUAL-CHAIN recurrence. Each WG
// interleaves layer-0 step r and layer-1 step s=r-1 in one instruction stream
// (r11 granule protocol per chain, independent gx0/gx1 buffers). L1's polls
// are one full round stale -> first-try hits; only L0's polls stay exposed.
// L1's input projection W_ih1 . seq0[s] is computed IN-KERNEL from hs0
// (already staged for L0): W_ih1 slice lives in LDS (110.6KB), W_hh0/W_hh1
// slices in registers. Deletes all L1 proj GEMMs and all seq0 global writes.
// Sequential chain: 2048 rounds -> 1025. LDS 159.7KB pins 1 WG/CU.
__global__ __launch_bounds__(RT, 1) void gru_rec_dual(
    const float* __restrict__ gi0,
    const float* __restrict__ w_hh0, const float* __restrict__ b_hh0,
    const float* __restrict__ w_hh1, const float* __restrict__ b_hh1,
    const float* __restrict__ w_ih1, const float* __restrict__ b_ih1,
    unsigned long long* __restrict__ gx0, unsigned long long* __restrict__ gx1,
    float* __restrict__ seq1, int t0, int Tc, int rounds)
{
  __shared__ float hs0[8][768];     // layer-0 h(t): rows 0-3 X, 4-7 Y
  __shared__ float hs1[8][768];     // layer-1 h(s)
  __shared__ float wih[36][768];    // W_ih1 slice: row (g*2+j2)*6+p
  const int wg = blockIdx.x;
  const int jg = wg & 63;
  const int sd = wg >> 6;
  const int j0 = jg * 12;
  const int tid = threadIdx.x;
  const int p  = tid >> 6;        // wave 0..5
  const int ks = tid & 63;        // lane

  // ---- W_hh0 / W_hh1 slices into registers; W_ih1 slice into LDS ----
  float4 wreg0[3][2][3], wreg1[3][2][3];
#pragma unroll
  for (int g = 0; g < 3; g++)
#pragma unroll
    for (int j2 = 0; j2 < 2; j2++)
#pragma unroll
      for (int kk = 0; kk < 3; kk++) {
        const size_t row = (size_t)(g * 768 + j0 + 2 * p + j2) * 768 + (kk * 64 + ks) * 4;
        wreg0[g][j2][kk] = *(const float4*)(w_hh0 + row);
        wreg1[g][j2][kk] = *(const float4*)(w_hh1 + row);
        *(float4*)&wih[(g * 2 + j2) * 6 + p][(kk * 64 + ks) * 4] =
            *(const float4*)(w_ih1 + row);
      }

  const int j2l = (ks >> 2) & 1;
  const int cl  = ks & 3;
  const int j_out = j0 + 2 * p + j2l;
  const float bh0r = b_hh0[j_out];
  const float bh0z = b_hh0[768 + j_out];
  const float bh0n = b_hh0[1536 + j_out];
  const float c1r  = b_ih1[j_out] + b_hh1[j_out];
  const float c1z  = b_ih1[768 + j_out] + b_hh1[768 + j_out];
  const float bi1n = b_ih1[1536 + j_out];
  const float bh1n = b_hh1[1536 + j_out];

  const int sbi = tid >> 6;           // 0..3 (staging batch-in-half, tid<256)
  const int sk  = tid & 63;

  const bool hi4 = (ks & 4) != 0;
  const bool hi2 = (ks & 2) != 0;
  const bool hi1 = (ks & 1) != 0;

  auto ladder = [&](vf2 (&a2)[3][2][4], float* r3) {
    float acc[3][2][4];
#pragma unroll
    for (int g = 0; g < 3; g++)
#pragma unroll
      for (int j2 = 0; j2 < 2; j2++)
#pragma unroll
        for (int c = 0; c < 4; c++) acc[g][j2][c] = a2[g][j2][c].x + a2[g][j2][c].y;
    float r12[3][4];
#pragma unroll
    for (int g = 0; g < 3; g++)
#pragma unroll
      for (int c = 0; c < 4; c++) {
        float send = hi4 ? acc[g][0][c] : acc[g][1][c];
        float keep = hi4 ? acc[g][1][c] : acc[g][0][c];
        r12[g][c] = keep + __shfl_xor(send, 4);
      }
    float r6[3][2];
#pragma unroll
    for (int g = 0; g < 3; g++)
#pragma unroll
      for (int c2 = 0; c2 < 2; c2++) {
        float send = hi2 ? r12[g][c2] : r12[g][2 + c2];
        float keep = hi2 ? r12[g][2 + c2] : r12[g][c2];
        r6[g][c2] = keep + __shfl_xor(send, 2);
      }
#pragma unroll
    for (int g = 0; g < 3; g++) {
      float send = hi1 ? r6[g][0] : r6[g][1];
      float keep = hi1 ? r6[g][1] : r6[g][0];
      r3[g] = keep + __shfl_xor(send, 1);
    }
#pragma unroll
    for (int g = 0; g < 3; g++) {
      r3[g] += __shfl_xor(r3[g], 8);
      r3[g] += __shfl_xor(r3[g], 16);
      r3[g] += __shfl_xor(r3[g], 32);
    }
  };

  auto dotreg = [&](const float4 (&wr)[3][2][3], const float (*h)[768], float* r3) {
    vf2 a2[3][2][4];
#pragma unroll
    for (int g = 0; g < 3; g++)
#pragma unroll
      for (int j2 = 0; j2 < 2; j2++)
#pragma unroll
        for (int c = 0; c < 4; c++) a2[g][j2][c] = (vf2)(0.f);
#pragma unroll
    for (int kk = 0; kk < 3; kk++) {
      const int off = (kk * 64 + ks) * 4;
      vf2 hlo[4], hhi[4];
#pragma unroll
      for (int c = 0; c < 4; c++) {
        float4 x = *(const float4*)(h[c] + off);
        hlo[c] = (vf2){x.x, x.y};
        hhi[c] = (vf2){x.z, x.w};
      }
#pragma unroll
      for (int g = 0; g < 3; g++)
#pragma unroll
        for (int j2 = 0; j2 < 2; j2++) {
          float4 w = wr[g][j2][kk];
          vf2 wlo = (vf2){w.x, w.y};
          vf2 whi = (vf2){w.z, w.w};
#pragma unroll
          for (int c = 0; c < 4; c++) {
            a2[g][j2][c] = __builtin_elementwise_fma(wlo, hlo[c], a2[g][j2][c]);
            a2[g][j2][c] = __builtin_elementwise_fma(whi, hhi[c], a2[g][j2][c]);
          }
        }
    }
    ladder(a2, r3);
  };

  auto dotlds = [&](const float (*h)[768], float* r3) {
    vf2 a2[3][2][4];
#pragma unroll
    for (int g = 0; g < 3; g++)
#pragma unroll
      for (int j2 = 0; j2 < 2; j2++)
#pragma unroll
        for (int c = 0; c < 4; c++) a2[g][j2][c] = (vf2)(0.f);
#pragma unroll
    for (int kk = 0; kk < 3; kk++) {
      const int off = (kk * 64 + ks) * 4;
      vf2 hlo[4], hhi[4];
#pragma unroll
      for (int c = 0; c < 4; c++) {
        float4 x = *(const float4*)(h[c] + off);
        hlo[c] = (vf2){x.x, x.y};
        hhi[c] = (vf2){x.z, x.w};
      }
#pragma unroll
      for (int g = 0; g < 3; g++)
#pragma unroll
        for (int j2 = 0; j2 < 2; j2++) {
          float4 w = *(const float4*)&wih[(g * 2 + j2) * 6 + p][off];
          vf2 wlo = (vf2){w.x, w.y};
          vf2 whi = (vf2){w.z, w.w};
#pragma unroll
          for (int c = 0; c < 4; c++) {
            a2[g][j2][c] = __builtin_elementwise_fma(wlo, hlo[c], a2[g][j2][c]);
            a2[g][j2][c] = __builtin_elementwise_fma(whi, hhi[c], a2[g][j2][c]);
          }
        }
    }
    ladder(a2, r3);
  };

  __syncthreads();   // wih ready

  for (int rr = 0; rr < rounds; rr++) {
    const int r = t0 + rr;            // layer-0 step
    const int s = r - 1;              // layer-1 step
    const bool doL0 = (r < 1024);
    const bool doL1 = (s >= 0);

#pragma unroll 1
    for (int half = 0; half < 2; half++) {
      const int hb = 4 * half;

      // gi0 loads hoisted above the staging sweep
      float g0r = 0.f, g0z = 0.f, g0n = 0.f;
      if (doL0 && ks < 8) {
        const float* gp = gi0 + ((size_t)(8 * sd + hb + cl) * Tc + rr) * 2304 + j_out;
        g0r = gp[0]; g0z = gp[768]; g0n = gp[1536];
      }

      // -------- combined staging sweep: gx0 tag r (fresh) + gx1 tag s (stale)
      if (tid < 256) {
        const unsigned long long* s0p =
            gx0 + (size_t)(r & 1) * 24576 + (size_t)(8 * sd + hb + sbi) * 768 + sk;
        unsigned long long v0[12];
#pragma unroll
        for (int i = 0; i < 12; i++)
          v0[i] = __hip_atomic_load(s0p + 64 * i, __ATOMIC_RELAXED, __HIP_MEMORY_SCOPE_AGENT);
        const unsigned long long* s1p = nullptr;
        unsigned long long v1[12];
        if (doL1) {
          s1p = gx1 + (size_t)(s & 1) * 24576 + (size_t)(8 * sd + hb + sbi) * 768 + sk;
#pragma unroll
          for (int i = 0; i < 12; i++)
            v1[i] = __hip_atomic_load(s1p + 64 * i, __ATOMIC_RELAXED, __HIP_MEMORY_SCOPE_AGENT);
        }
        const unsigned w0 = (unsigned)r, w1 = (unsigned)s;
        while (true) {
          unsigned miss = 0;
#pragma unroll
          for (int i = 0; i < 12; i++)
            miss |= (unsigned)((unsigned)(v0[i] >> 32) < w0);
          if (doL1)
#pragma unroll
            for (int i = 0; i < 12; i++)
              miss |= (unsigned)((unsigned)(v1[i] >> 32) < w1);
          if (!miss) break;
          __builtin_amdgcn_s_sleep(1);
#pragma unroll
          for (int i = 0; i < 12; i++)
            if ((unsigned)(v0[i] >> 32) < w0)
              v0[i] = __hip_atomic_load(s0p + 64 * i, __ATOMIC_RELAXED, __HIP_MEMORY_SCOPE_AGENT);
          if (doL1)
#pragma unroll
            for (int i = 0; i < 12; i++)
              if ((unsigned)(v1[i] >> 32) < w1)
                v1[i] = __hip_atomic_load(s1p + 64 * i, __ATOMIC_RELAXED, __HIP_MEMORY_SCOPE_AGENT);
        }
#pragma unroll
        for (int i = 0; i < 12; i++)
          hs0[hb + sbi][sk + 64 * i] = __uint_as_float((unsigned)v0[i]);
        if (doL1)
#pragma unroll
          for (int i = 0; i < 12; i++)
            hs1[hb + sbi][sk + 64 * i] = __uint_as_float((unsigned)v1[i]);
      }
      __syncthreads();   // hs0/hs1 for this half ready

      // -------- layer-0 compute --------
      if (doL0) {
        float r3[3];
        dotreg(wreg0, &hs0[hb], r3);
        if (ks < 8) {
          float hp = hs0[hb + cl][j_out];
          float rg = 1.f / (1.f + __expf(-(g0r + r3[0] + bh0r)));
          float zg = 1.f / (1.f + __expf(-(g0z + r3[1] + bh0z)));
          float ng = tanhf(g0n + rg * (r3[2] + bh0n));
          float hv = (1.f - zg) * ng + zg * hp;
          __hip_atomic_store(
              gx0 + (size_t)((r + 1) & 1) * 24576 + (size_t)(8 * sd + hb + cl) * 768 + j_out,
              ((unsigned long long)(unsigned)(r + 1) << 32) |
                  (unsigned long long)__float_as_uint(hv),
              __ATOMIC_RELAXED, __HIP_MEMORY_SCOPE_AGENT);
        }
      }

      // -------- layer-1 compute: W_hh1.h1(s) + W_ih1.seq0[s] (= hs0) --------
      if (doL1) {
        float rhh[3], rih[3];
        dotreg(wreg1, &hs1[hb], rhh);
        dotlds(&hs0[hb], rih);
        if (ks < 8) {
          float hp = hs1[hb + cl][j_out];
          float rg = 1.f / (1.f + __expf(-(rih[0] + rhh[0] + c1r)));
          float zg = 1.f / (1.f + __expf(-(rih[1] + rhh[1] + c1z)));
          float ng = tanhf(rih[2] + bi1n + rg * (rhh[2] + bh1n));
          float hv = (1.f - zg) * ng + zg * hp;
          __hip_atomic_store(
              gx1 + (size_t)((s + 1) & 1) * 24576 + (size_t)(8 * sd + hb + cl) * 768 + j_out,
              ((unsigned long long)(unsigned)(s + 1) << 32) |
                  (unsigned long long)__float_as_uint(hv),
              __ATOMIC_RELAXED, __HIP_MEMORY_SCOPE_AGENT);
          seq1[((size_t)(8 * sd + hb + cl) * 1024 + s) * 768 + j_out] = hv;
        }
      }
      __syncthreads();   // half done; hs safe to overwrite next half/round
    }
  }
}

extern "C" void kernel_launch(void* const* d_in, const int* in_sizes, int n_in,
                              void* d_out, int out_size, void* d_ws, size_t ws_size,
                              hipStream_t stream) {
  const float* feat  = (const float*)d_in[0];
  const float* w_ih0 = (const float*)d_in[2];
  const float* w_hh0 = (const float*)d_in[3];
  const float* b_ih0 = (const float*)d_in[4];
  const float* b_hh0 = (const float*)d_in[5];
  const float* w_ih1 = (const float*)d_in[6];
  const float* w_hh1 = (const float*)d_in[7];
  const float* b_ih1 = (const float*)d_in[8];
  const float* b_hh1 = (const float*)d_in[9];
  const float* fc_w  = (const float*)d_in[10];
  const float* fc_b  = (const float*)d_in[11];
  const float* out_w = (const float*)d_in[12];
  const float* out_b = (const float*)d_in[13];
  float* out = (float*)d_out;

  const int Tc = 256;
  const int McChunk = 32 * Tc;

  float* proj = (float*)d_ws;                               // 18,874,368 f
  float* seq1 = proj + (size_t)18874368;                    // 25,165,824 f
  unsigned long long* gx0 = (unsigned long long*)(seq1 + (size_t)25165824);
  unsigned long long* gx1 = gx0 + 49152;                    // each 2x24576 u64

  // single memset for both granule buffers: tags=0 (h(0)=0, poll 0 passes)
  hipMemsetAsync(gx0, 0, 2 * 393216, stream);

  for (int c = 0; c < 4; c++) {
    gemm_bt_f32<<<dim3(36, McChunk / 128), dim3(256), 0, stream>>>(
        feat, w_ih0, b_ih0, proj, McChunk, 2304, 768, 8, 1024, c * Tc, 0);
    gru_rec_dual<<<dim3(RNWG), dim3(RT), 0, stream>>>(
        proj, w_hh0, b_hh0, w_hh1, b_hh1, w_ih1, b_ih1,
        gx0, gx1, seq1, c * Tc, Tc, (c == 3) ? Tc + 1 : Tc);
  }
  // ---- fc + SELU ----
  gemm_bt_f32<<<dim3(8, 256), dim3(256), 0, stream>>>(
      seq1, fc_w, fc_b, proj, 32768, 512, 768, 15, 32768, 0, 1);
  // ---- out + tanh ----
  gemm_bt_f32<<<dim3(1, 256), dim3(256), 0, stream>>>(
      proj, out_w, out_b, out, 32768, 39, 512, 15, 32768, 0, 2);
}

// Round 11
// 13765.276 us; speedup vs baseline: 2.3566x; 2.3566x over previous
//
#include <hip/hip_runtime.h>
#include <cstdint>

typedef float vf2 __attribute__((ext_vector_type(2)));

#define GB_M 128
#define GB_N 64
#define GB_K 16

// C[m,n] = act( sum_k A[row(m),k]*B[n,k] + bias[n] )
__global__ __launch_bounds__(256) void gemm_bt_f32(
    const float* __restrict__ A, const float* __restrict__ B,
    const float* __restrict__ bias, float* __restrict__ C,
    int Mc, int N, int K, int tc_shift, int Tfull, int t0, int act)
{
  __shared__ float As[GB_K][GB_M + 4];
  __shared__ float Bs[GB_K][GB_N + 4];
  const int tid = threadIdx.x;
  const int m0 = blockIdx.y * GB_M;
  const int n0 = blockIdx.x * GB_N;
  const int tx = tid & 15;
  const int ty = tid >> 4;

  const int tcmask = (1 << tc_shift) - 1;
  int arow[2];
#pragma unroll
  for (int i = 0; i < 2; i++) {
    int f = tid + i * 256;
    int row = f >> 2;
    int rc = m0 + row;
    arow[i] = (rc >> tc_shift) * Tfull + t0 + (rc & tcmask);
  }
  const int akq = tid & 3;
  const int brow = tid >> 2;
  const int bn = n0 + brow;

  vf2 acc2[4][4];
#pragma unroll
  for (int i = 0; i < 4; i++)
#pragma unroll
    for (int j = 0; j < 4; j++) acc2[i][j] = (vf2)(0.f);

  for (int k0 = 0; k0 < K; k0 += GB_K) {
#pragma unroll
    for (int i = 0; i < 2; i++) {
      int f = tid + i * 256;
      int row = f >> 2;
      float4 v = *(const float4*)(A + (size_t)arow[i] * K + k0 + akq * 4);
      As[akq * 4 + 0][row] = v.x; As[akq * 4 + 1][row] = v.y;
      As[akq * 4 + 2][row] = v.z; As[akq * 4 + 3][row] = v.w;
    }
    {
      float4 v = make_float4(0.f, 0.f, 0.f, 0.f);
      if (bn < N) v = *(const float4*)(B + (size_t)bn * K + k0 + akq * 4);
      Bs[akq * 4 + 0][brow] = v.x; Bs[akq * 4 + 1][brow] = v.y;
      Bs[akq * 4 + 2][brow] = v.z; Bs[akq * 4 + 3][brow] = v.w;
    }
    __syncthreads();
#pragma unroll
    for (int k = 0; k < GB_K; k++) {
      float4 a0 = *(const float4*)&As[k][ty * 8];
      float4 a1 = *(const float4*)&As[k][ty * 8 + 4];
      float4 b0 = *(const float4*)&Bs[k][tx * 4];
      vf2 a2[4];
      a2[0] = (vf2){a0.x, a0.y}; a2[1] = (vf2){a0.z, a0.w};
      a2[2] = (vf2){a1.x, a1.y}; a2[3] = (vf2){a1.z, a1.w};
      float bv[4] = {b0.x, b0.y, b0.z, b0.w};
#pragma unroll
      for (int j = 0; j < 4; j++) {
        vf2 bs = (vf2){bv[j], bv[j]};
#pragma unroll
        for (int ip = 0; ip < 4; ip++)
          acc2[ip][j] = __builtin_elementwise_fma(a2[ip], bs, acc2[ip][j]);
      }
    }
    __syncthreads();
  }

#pragma unroll
  for (int j = 0; j < 4; j++) {
    int n = n0 + tx * 4 + j;
    if (n >= N) continue;
    float bz = bias[n];
#pragma unroll
    for (int i = 0; i < 8; i++) {
      int m = m0 + ty * 8 + i;
      float x = ((i & 1) ? acc2[i >> 1][j].y : acc2[i >> 1][j].x) + bz;
      if (act == 1) {
        x = 1.0507009873554805f * (x > 0.f ? x : 1.6732632423543772f * (__expf(x) - 1.f));
      } else if (act == 2) {
        x = tanhf(x);
      }
      C[(size_t)m * N + n] = x;
    }
  }
}

#define RT 384
#define RNWG 256

// Round-13: MERGED single round per step + self-publishing granules
// (the untested quadrant). r11's granule protocol stays byte-identical per
// granule: {tag:u32 | h:f32bits}, one agent-scope atomic store right after
// the gate math (store IS the publish, mid-round). What changes vs r11:
// ONE combined poll+stage sweep per STEP (all 8 batches, 24 granules/thread,
// lane-adjacent coalesced) instead of two per-half sweeps. Barriers stay 2
// per step (BAR_A: hs ready; BAR_B: hs reads done before next overwrite).
// Per-step chain: poll(hit, granules stored a full round earlier) + 1 stage
// RT + dotA -> storeA (publish) + dotB -> storeB. Removes one stage-RT +
// one poll-detect per step vs r11. Register audit (round-10 lesson): wreg 72
// + sweep 48 + misc < 512/wave cap at launch_bounds(384,1) -> no spill.
__global__ __launch_bounds__(RT, 1) void gru_rec(
    const float* __restrict__ gi, const float* __restrict__ w_hh,
    const float* __restrict__ b_hh, unsigned long long* __restrict__ gx,
    float* __restrict__ seq, int t0, int Tc)
{
  __shared__ float hs[8][776];    // rows 0-3: X batches, 4-7: Y batches
  const int wg = blockIdx.x;
  const int jg = wg & 63;
  const int sd = wg >> 6;
  const int j0 = jg * 12;
  const int tid = threadIdx.x;
  const int p  = tid >> 6;        // wave 0..5
  const int ks = tid & 63;        // lane

  // ---- W slice into registers: [g][j2][kk], row g*768+j0+2p+j2, 16B at (kk*64+ks)*4
  float4 wreg[3][2][3];
#pragma unroll
  for (int g = 0; g < 3; g++)
#pragma unroll
    for (int j2 = 0; j2 < 2; j2++)
#pragma unroll
      for (int kk = 0; kk < 3; kk++)
        wreg[g][j2][kk] = *(const float4*)(
            w_hh + (size_t)(g * 768 + j0 + 2 * p + j2) * 768 + (kk * 64 + ks) * 4);

  const int j2l = (ks >> 2) & 1;
  const int cl  = ks & 3;
  const int j_out  = j0 + 2 * p + j2l;
  const int bX_out = 8 * sd + cl;
  const int bY_out = 8 * sd + 4 + cl;
  const float bhr = b_hh[j_out];
  const float bhz = b_hh[768 + j_out];
  const float bhn = b_hh[1536 + j_out];

  // staging: tid<256; 32 threads per batch (sbi=tid>>5), thread sk covers
  // dims {sk + 32*i, i=0..23} -> lane-adjacent coalesced granule loads
  const int sbi = tid >> 5;           // 0..7 (batch within superdomain)
  const int sk  = tid & 31;

  const bool hi4 = (ks & 4) != 0;
  const bool hi2 = (ks & 2) != 0;
  const bool hi1 = (ks & 1) != 0;

  for (int tt = 0; tt < Tc; tt++) {
    const int t = t0 + tt;
    const unsigned wantt = (unsigned)t;

    // gi loads for both halves — issued early, latency hides under the sweep
    float gXr = 0.f, gXz = 0.f, gXn = 0.f;
    float gYr = 0.f, gYz = 0.f, gYn = 0.f;
    if (ks < 8) {
      const float* gX = gi + ((size_t)bX_out * Tc + tt) * 2304 + j_out;
      gXr = gX[0]; gXz = gX[768]; gXn = gX[1536];
      const float* gY = gi + ((size_t)bY_out * Tc + tt) * 2304 + j_out;
      gYr = gY[0]; gYz = gY[768]; gYn = gY[1536];
    }

    // -------- ONE combined sweep: all 8 batches, tags >= t --------
    if (tid < 256) {
      const unsigned long long* src =
          gx + (size_t)(t & 1) * 24576 + (size_t)(8 * sd + sbi) * 768 + sk;
      unsigned long long v[24];
#pragma unroll
      for (int i = 0; i < 24; i++)
        v[i] = __hip_atomic_load(src + 32 * i, __ATOMIC_RELAXED, __HIP_MEMORY_SCOPE_AGENT);
      while (true) {
        unsigned miss = 0;
#pragma unroll
        for (int i = 0; i < 24; i++)
          miss |= (unsigned)((unsigned)(v[i] >> 32) < wantt);
        if (!miss) break;
        __builtin_amdgcn_s_sleep(1);
#pragma unroll
        for (int i = 0; i < 24; i++)
          if ((unsigned)(v[i] >> 32) < wantt)
            v[i] = __hip_atomic_load(src + 32 * i, __ATOMIC_RELAXED, __HIP_MEMORY_SCOPE_AGENT);
      }
#pragma unroll
      for (int i = 0; i < 24; i++)
        hs[sbi][sk + 32 * i] = __uint_as_float((unsigned)v[i]);
    }
    __syncthreads();   // BAR_A: hs (all 8 batches) ready

    // ---------------- dot + gates + store, X half (rows 0-3) ----------------
    float r3[3];
    {
      vf2 a2[3][2][4];
#pragma unroll
      for (int g = 0; g < 3; g++)
#pragma unroll
        for (int j2 = 0; j2 < 2; j2++)
#pragma unroll
          for (int c = 0; c < 4; c++) a2[g][j2][c] = (vf2)(0.f);
#pragma unroll
      for (int kk = 0; kk < 3; kk++) {
        const int off = (kk * 64 + ks) * 4;
        vf2 hlo[4], hhi[4];
#pragma unroll
        for (int c = 0; c < 4; c++) {
          float4 h = *(const float4*)(&hs[c][0] + off);
          hlo[c] = (vf2){h.x, h.y};
          hhi[c] = (vf2){h.z, h.w};
        }
#pragma unroll
        for (int g = 0; g < 3; g++)
#pragma unroll
          for (int j2 = 0; j2 < 2; j2++) {
            float4 w = wreg[g][j2][kk];
            vf2 wlo = (vf2){w.x, w.y};
            vf2 whi = (vf2){w.z, w.w};
#pragma unroll
            for (int c = 0; c < 4; c++) {
              a2[g][j2][c] = __builtin_elementwise_fma(wlo, hlo[c], a2[g][j2][c]);
              a2[g][j2][c] = __builtin_elementwise_fma(whi, hhi[c], a2[g][j2][c]);
            }
          }
      }
      float acc[3][2][4];
#pragma unroll
      for (int g = 0; g < 3; g++)
#pragma unroll
        for (int j2 = 0; j2 < 2; j2++)
#pragma unroll
          for (int c = 0; c < 4; c++) acc[g][j2][c] = a2[g][j2][c].x + a2[g][j2][c].y;

      float r12[3][4];
#pragma unroll
      for (int g = 0; g < 3; g++)
#pragma unroll
        for (int c = 0; c < 4; c++) {
          float send = hi4 ? acc[g][0][c] : acc[g][1][c];
          float keep = hi4 ? acc[g][1][c] : acc[g][0][c];
          r12[g][c] = keep + __shfl_xor(send, 4);
        }
      float r6[3][2];
#pragma unroll
      for (int g = 0; g < 3; g++)
#pragma unroll
        for (int c2 = 0; c2 < 2; c2++) {
          float send = hi2 ? r12[g][c2] : r12[g][2 + c2];
          float keep = hi2 ? r12[g][2 + c2] : r12[g][c2];
          r6[g][c2] = keep + __shfl_xor(send, 2);
        }
#pragma unroll
      for (int g = 0; g < 3; g++) {
        float send = hi1 ? r6[g][0] : r6[g][1];
        float keep = hi1 ? r6[g][1] : r6[g][0];
        r3[g] = keep + __shfl_xor(send, 1);
      }
#pragma unroll
      for (int g = 0; g < 3; g++) {
        r3[g] += __shfl_xor(r3[g], 8);
        r3[g] += __shfl_xor(r3[g], 16);
        r3[g] += __shfl_xor(r3[g], 32);
      }
    }
    if (ks < 8) {
      float hp = hs[cl][j_out];
      float r = 1.f / (1.f + __expf(-(gXr + r3[0] + bhr)));
      float z = 1.f / (1.f + __expf(-(gXz + r3[1] + bhz)));
      float n = tanhf(gXn + r * (r3[2] + bhn));
      float hv = (1.f - z) * n + z * hp;
      // granule store IS the publish (tag t+1 travels with the data)
      __hip_atomic_store(
          gx + (size_t)((t + 1) & 1) * 24576 + (size_t)bX_out * 768 + j_out,
          ((unsigned long long)(unsigned)(t + 1) << 32) |
              (unsigned long long)__float_as_uint(hv),
          __ATOMIC_RELAXED, __HIP_MEMORY_SCOPE_AGENT);
      seq[((size_t)bX_out * 1024 + t) * 768 + j_out] = hv;
    }

    // ---------------- dot + gates + store, Y half (rows 4-7) ----------------
    {
      vf2 a2[3][2][4];
#pragma unroll
      for (int g = 0; g < 3; g++)
#pragma unroll
        for (int j2 = 0; j2 < 2; j2++)
#pragma unroll
          for (int c = 0; c < 4; c++) a2[g][j2][c] = (vf2)(0.f);
#pragma unroll
      for (int kk = 0; kk < 3; kk++) {
        const int off = (kk * 64 + ks) * 4;
        vf2 hlo[4], hhi[4];
#pragma unroll
        for (int c = 0; c < 4; c++) {
          float4 h = *(const float4*)(&hs[4 + c][0] + off);
          hlo[c] = (vf2){h.x, h.y};
          hhi[c] = (vf2){h.z, h.w};
        }
#pragma unroll
        for (int g = 0; g < 3; g++)
#pragma unroll
          for (int j2 = 0; j2 < 2; j2++) {
            float4 w = wreg[g][j2][kk];
            vf2 wlo = (vf2){w.x, w.y};
            vf2 whi = (vf2){w.z, w.w};
#pragma unroll
            for (int c = 0; c < 4; c++) {
              a2[g][j2][c] = __builtin_elementwise_fma(wlo, hlo[c], a2[g][j2][c]);
              a2[g][j2][c] = __builtin_elementwise_fma(whi, hhi[c], a2[g][j2][c]);
            }
          }
      }
      float acc[3][2][4];
#pragma unroll
      for (int g = 0; g < 3; g++)
#pragma unroll
        for (int j2 = 0; j2 < 2; j2++)
#pragma unroll
          for (int c = 0; c < 4; c++) acc[g][j2][c] = a2[g][j2][c].x + a2[g][j2][c].y;

      float r12[3][4];
#pragma unroll
      for (int g = 0; g < 3; g++)
#pragma unroll
        for (int c = 0; c < 4; c++) {
          float send = hi4 ? acc[g][0][c] : acc[g][1][c];
          float keep = hi4 ? acc[g][1][c] : acc[g][0][c];
          r12[g][c] = keep + __shfl_xor(send, 4);
        }
      float r6[3][2];
#pragma unroll
      for (int g = 0; g < 3; g++)
#pragma unroll
        for (int c2 = 0; c2 < 2; c2++) {
          float send = hi2 ? r12[g][c2] : r12[g][2 + c2];
          float keep = hi2 ? r12[g][2 + c2] : r12[g][c2];
          r6[g][c2] = keep + __shfl_xor(send, 2);
        }
#pragma unroll
      for (int g = 0; g < 3; g++) {
        float send = hi1 ? r6[g][0] : r6[g][1];
        float keep = hi1 ? r6[g][1] : r6[g][0];
        r3[g] = keep + __shfl_xor(send, 1);
      }
#pragma unroll
      for (int g = 0; g < 3; g++) {
        r3[g] += __shfl_xor(r3[g], 8);
        r3[g] += __shfl_xor(r3[g], 16);
        r3[g] += __shfl_xor(r3[g], 32);
      }
    }
    if (ks < 8) {
      float hp = hs[4 + cl][j_out];
      float r = 1.f / (1.f + __expf(-(gYr + r3[0] + bhr)));
      float z = 1.f / (1.f + __expf(-(gYz + r3[1] + bhz)));
      float n = tanhf(gYn + r * (r3[2] + bhn));
      float hv = (1.f - z) * n + z * hp;
      __hip_atomic_store(
          gx + (size_t)((t + 1) & 1) * 24576 + (size_t)bY_out * 768 + j_out,
          ((unsigned long long)(unsigned)(t + 1) << 32) |
              (unsigned long long)__float_as_uint(hv),
          __ATOMIC_RELAXED, __HIP_MEMORY_SCOPE_AGENT);
      seq[((size_t)bY_out * 1024 + t) * 768 + j_out] = hv;
    }
    __syncthreads();   // BAR_B: all hs reads done; next stage may overwrite
  }
}

extern "C" void kernel_launch(void* const* d_in, const int* in_sizes, int n_in,
                              void* d_out, int out_size, void* d_ws, size_t ws_size,
                              hipStream_t stream) {
  const float* feat  = (const float*)d_in[0];
  const float* w_ih0 = (const float*)d_in[2];
  const float* w_hh0 = (const float*)d_in[3];
  const float* b_ih0 = (const float*)d_in[4];
  const float* b_hh0 = (const float*)d_in[5];
  const float* w_ih1 = (const float*)d_in[6];
  const float* w_hh1 = (const float*)d_in[7];
  const float* b_ih1 = (const float*)d_in[8];
  const float* b_hh1 = (const float*)d_in[9];
  const float* fc_w  = (const float*)d_in[10];
  const float* fc_b  = (const float*)d_in[11];
  const float* out_w = (const float*)d_in[12];
  const float* out_b = (const float*)d_in[13];
  float* out = (float*)d_out;

  const int Tc = 256;
  const int McChunk = 32 * Tc;

  float* proj = (float*)d_ws;                               // 18,874,368 f
  float* seq  = proj + (size_t)32 * Tc * 2304;              // 25,165,824 f
  unsigned long long* gx = (unsigned long long*)(seq + (size_t)25165824);
  const size_t GXB = (size_t)2 * 24576 * 8;                 // 393,216 B

  // ---- layer 0 ----
  hipMemsetAsync(gx, 0, GXB, stream);   // tags=0, h=0 -> h(0)=0, poll t=0 passes
  for (int c = 0; c < 4; c++) {
    gemm_bt_f32<<<dim3(36, McChunk / 128), dim3(256), 0, stream>>>(
        feat, w_ih0, b_ih0, proj, McChunk, 2304, 768, 8, 1024, c * Tc, 0);
    gru_rec<<<dim3(RNWG), dim3(RT), 0, stream>>>(
        proj, w_hh0, b_hh0, gx, seq, c * Tc, Tc);
  }
  // ---- layer 1 ----
  hipMemsetAsync(gx, 0, GXB, stream);
  for (int c = 0; c < 4; c++) {
    gemm_bt_f32<<<dim3(36, McChunk / 128), dim3(256), 0, stream>>>(
        seq, w_ih1, b_ih1, proj, McChunk, 2304, 768, 8, 1024, c * Tc, 0);
    gru_rec<<<dim3(RNWG), dim3(RT), 0, stream>>>(
        proj, w_hh1, b_hh1, gx, seq, c * Tc, Tc);
  }
  // ---- fc + SELU ----
  gemm_bt_f32<<<dim3(8, 256), dim3(256), 0, stream>>>(
      seq, fc_w, fc_b, proj, 32768, 512, 768, 15, 32768, 0, 1);
  // ---- out + tanh ----
  gemm_bt_f32<<<dim3(1, 256), dim3(256), 0, stream>>>(
      proj, out_w, out_b, out, 32768, 39, 512, 15, 32768, 0, 2);
}